// Round 9
// baseline (348.732 us; speedup 1.0000x reference)
//
#include <hip/hip_runtime.h>
#include <hip/hip_fp16.h>
#include <cstdint>

#define TABLE_MASK 0x3FFFFFu   // 2^22 - 1
#define P2 2654435761u
#define P3 805459861u

#define ZE 132                  // w' = true_w + 1, w' in [0,131]
#define NB2 16384               // bins: iy*128 + ix
#define SCAN2 16                // scanA blocks (16384/1024)

__device__ __forceinline__ float sigmoidf_(float x) { return 1.0f / (1.0f + expf(-x)); }

__device__ __forceinline__ uint32_t f2h2(float a, float b) {
    __half2 h = __floats2half2_rn(a, b);
    return *reinterpret_cast<uint32_t*>(&h);
}
__device__ __forceinline__ __half2 u2h2(uint32_t u) {
    return *reinterpret_cast<__half2*>(&u);
}
__device__ __forceinline__ uint32_t h2u(__half2 h) {
    return *reinterpret_cast<uint32_t*>(&h);
}

// ---------- prepass: xy-combined fp16 volume ----------
// Record at (ix,iy,w'): per feature-pair m: {SEX, dEX, SDX, dDX} as half2 -> uint4.
//   EX(v) = R(ix-1,v)+R(ix,v)+R(ix+1,v), DX(v) = R(ix+2,v)-R(ix-1,v)
//   SEX = EX(iy-1)+EX(iy)+EX(iy+1), dEX = EX(iy+2)-EX(iy-1); SDX/dDX same from DX.
// Point value at slice w: (SEX + wy*dEX) + wx*(SDX + wy*dDX).
// Layout: uint index = (((iy*128 + ix)*ZE) + w') * 24, 4 z-records contiguous (384 B).
__global__ __launch_bounds__(256, 4)
void build_exdy_kernel(const float4* __restrict__ gauss,
                       const float4* __restrict__ vmf,
                       uint32_t* __restrict__ exdy)
{
    __shared__ uint32_t Rt[35][35][6];    // 29.4 KB, fp16x2 per feature-pair
    int blk  = blockIdx.x;                // tile*ZE + w'  (consecutive blocks share tile)
    int wp   = blk % ZE;
    int tile = blk / ZE;                  // 0..15
    int ix0 = (tile & 3) * 32;
    int iy0 = (tile >> 2) * 32;
    uint32_t w = (uint32_t)(wp - 1);      // true corner z (numpy uint32 wrap)
    int t = threadIdx.x;

    // stage 35x35 corner records, batched for MLP
    float4 G[5], V0[5], V1[5];
    int ls[5];
#pragma unroll
    for (int it = 0; it < 5; ++it) {
        int l = t + it * 256;
        ls[it] = (l < 1225) ? l : -1;
        if (ls[it] >= 0) {
            int lu = l % 35, lv = l / 35;
            uint32_t u = (uint32_t)(ix0 - 1 + lu);
            uint32_t v = (uint32_t)(iy0 - 1 + lv);
            uint32_t h = (u ^ (v * P2) ^ (w * P3)) & TABLE_MASK;
            G[it]  = gauss[h];
            V0[it] = vmf[(size_t)2 * h];
            V1[it] = vmf[(size_t)2 * h + 1];
        }
    }
#pragma unroll
    for (int it = 0; it < 5; ++it) if (ls[it] >= 0) {
        int lu = ls[it] % 35, lv = ls[it] / 35;
        uint32_t* c = Rt[lv][lu];
        c[0] = f2h2(G[it].x,  G[it].y);
        c[1] = f2h2(G[it].z,  G[it].w);
        c[2] = f2h2(V0[it].x, V0[it].y);
        c[3] = f2h2(V0[it].z, V0[it].w);
        c[4] = f2h2(V1[it].x, V1[it].y);
        c[5] = f2h2(V1[it].z, V1[it].w);
    }
    __syncthreads();

    // compute 32x32 outputs for this (tile, w')
#pragma unroll
    for (int oi = 0; oi < 4; ++oi) {
        int o  = t + oi * 256;
        int lx = o & 31, ly = o >> 5;
        int ix = ix0 + lx, iy = iy0 + ly;
        size_t ri = ((size_t)iy * 128 + (size_t)ix) * ZE + (size_t)wp;
        uint32_t* dst = exdy + ri * 24;
#pragma unroll
        for (int m = 0; m < 6; ++m) {
            __half2 EX[4], DX[4];
#pragma unroll
            for (int r = 0; r < 4; ++r) {
                __half2 r0 = u2h2(Rt[ly + r][lx    ][m]);
                __half2 r1 = u2h2(Rt[ly + r][lx + 1][m]);
                __half2 r2 = u2h2(Rt[ly + r][lx + 2][m]);
                __half2 r3 = u2h2(Rt[ly + r][lx + 3][m]);
                EX[r] = __hadd2(__hadd2(r0, r1), r2);
                DX[r] = __hsub2(r3, r0);
            }
            __half2 SEX = __hadd2(__hadd2(EX[0], EX[1]), EX[2]);
            __half2 dEX = __hsub2(EX[3], EX[0]);
            __half2 SDX = __hadd2(__hadd2(DX[0], DX[1]), DX[2]);
            __half2 dDX = __hsub2(DX[3], DX[0]);
            *(uint4*)(dst + m * 4) = make_uint4(h2u(SEX), h2u(dEX), h2u(SDX), h2u(dDX));
        }
    }
}

// ---------- sort machinery (raster (iy,ix) bins, matches table layout) ----------
__device__ __forceinline__ int bin_key2(float px, float py)
{
    float x = ((px + 10.0f) / 20.0f) * 128.0f;
    float y = ((py + 10.0f) / 20.0f) * 128.0f;
    int ix = min(max((int)floorf(x), 0), 127);
    int iy = min(max((int)floorf(y), 0), 127);
    return iy * 128 + ix;
}

__global__ __launch_bounds__(256)
void hist_kernel(const float* __restrict__ pos, uint32_t* __restrict__ hist, int n)
{
    int p = blockIdx.x * blockDim.x + threadIdx.x;
    if (p >= n) return;
    atomicAdd(&hist[bin_key2(pos[3 * p], pos[3 * p + 1])], 1u);
}

__global__ __launch_bounds__(1024)
void scanA_kernel(const uint32_t* __restrict__ hist,
                  uint32_t* __restrict__ cursor,
                  uint32_t* __restrict__ sums)
{
    __shared__ uint32_t buf[1024];
    int t = threadIdx.x;
    int base = blockIdx.x * 1024;
    uint32_t v = hist[base + t];
    buf[t] = v;
    __syncthreads();
    for (int off = 1; off < 1024; off <<= 1) {
        uint32_t x = (t >= off) ? buf[t - off] : 0u;
        __syncthreads();
        buf[t] += x;
        __syncthreads();
    }
    cursor[base + t] = buf[t] - v;
    if (t == 1023) sums[blockIdx.x] = buf[t];
}

__global__ __launch_bounds__(SCAN2)
void scanB_kernel(const uint32_t* __restrict__ sums, uint32_t* __restrict__ offs)
{
    __shared__ uint32_t buf[SCAN2];
    int t = threadIdx.x;
    uint32_t v = sums[t];
    buf[t] = v;
    __syncthreads();
    for (int off = 1; off < SCAN2; off <<= 1) {
        uint32_t x = (t >= off) ? buf[t - off] : 0u;
        __syncthreads();
        buf[t] += x;
        __syncthreads();
    }
    offs[t] = buf[t] - v;
}

__global__ __launch_bounds__(256)
void scatter_kernel(const float* __restrict__ pos,
                    uint32_t* __restrict__ cursor,
                    const uint32_t* __restrict__ offs,
                    float4* __restrict__ sortedPts, int n)
{
    int p = blockIdx.x * blockDim.x + threadIdx.x;
    if (p >= n) return;
    float px = pos[3 * p], py = pos[3 * p + 1], pz = pos[3 * p + 2];
    int k = bin_key2(px, py);
    uint32_t slot = offs[k >> 10] + atomicAdd(&cursor[k], 1u);
    sortedPts[slot] = make_float4(px, py, pz, __uint_as_float((uint32_t)p));
}

// ---------- main: one contiguous 384 B read per point ----------
__global__ __launch_bounds__(256, 2)
void vapl_grid_sorted_kernel(const float4* __restrict__ sortedPts,
                             const uint32_t* __restrict__ exdy,
                             float* __restrict__ out,   // [N*4] then [N*7], f32
                             int n)
{
    int bid = blockIdx.x;
    int nb  = gridDim.x;
    int b2  = ((nb & 7) == 0) ? ((bid & 7) * (nb >> 3) + (bid >> 3)) : bid;
    int s = b2 * (int)blockDim.x + (int)threadIdx.x;
    if (s >= n) return;

    float4 pt = sortedPts[s];
    int p = (int)__float_as_uint(pt.w);

    float x = ((pt.x + 10.0f) / 20.0f) * 128.0f;
    float y = ((pt.y + 10.0f) / 20.0f) * 128.0f;
    float z = ((pt.z + 10.0f) / 20.0f) * 128.0f;

    float fx = floorf(x), fy = floorf(y), fz = floorf(z);
    int ix = (int)fx, iy = (int)fy, iz = (int)fz;
    float wx = x - fx, wy = y - fy, wz = z - fz;

    float az[4] = {1.0f - wz, 1.0f, 1.0f, wz};
    __half2 wx2 = __float2half2_rn(wx);
    __half2 wy2 = __float2half2_rn(wy);

    // record for (ix,iy,w'=iz); 4 z-records are contiguous: 24 uint4 = 384 B
    size_t ri = ((size_t)iy * 128 + (size_t)ix) * ZE + (size_t)iz;
    const uint4* q = (const uint4*)(exdy + ri * 24);
    uint4 r[24];
#pragma unroll
    for (int j = 0; j < 24; ++j) r[j] = q[j];

    float acc[12] = {0.f,0.f,0.f,0.f,0.f,0.f,0.f,0.f,0.f,0.f,0.f,0.f};
#pragma unroll
    for (int k = 0; k < 4; ++k) {
        float azk = az[k];
#pragma unroll
        for (int m = 0; m < 6; ++m) {
            uint4 u4 = r[k * 6 + m];
            __half2 t1 = __hfma2(wy2, u2h2(u4.y), u2h2(u4.x));   // SEX + wy*dEX
            __half2 t2 = __hfma2(wy2, u2h2(u4.w), u2h2(u4.z));   // SDX + wy*dDX
            __half2 tv = __hfma2(wx2, t2, t1);
            float2 f = __half22float2(tv);
            acc[2*m]     = fmaf(azk, f.x, acc[2*m]);
            acc[2*m + 1] = fmaf(azk, f.y, acc[2*m + 1]);
        }
    }

    float m0 = sigmoidf_(acc[0]) * 20.0f - 10.0f;
    float m1 = sigmoidf_(acc[1]) * 20.0f - 10.0f;
    float m2 = sigmoidf_(acc[2]) * 20.0f - 10.0f;
    float var = fmaxf(acc[3], 0.0f) + log1pf(expf(-fabsf(acc[3])));

    float sharp = expf(acc[4]);
    float nrm = fmaxf(sqrtf(acc[5]*acc[5] + acc[6]*acc[6] + acc[7]*acc[7]), 1e-12f);
    float a0 = acc[5] / nrm, a1 = acc[6] / nrm, a2 = acc[7] / nrm;
    float amp0 = sigmoidf_(acc[8]);
    float amp1 = sigmoidf_(acc[9]);
    float amp2 = sigmoidf_(acc[10]);

    float* og = out + (size_t)p * 4;
    *(float4*)og = make_float4(m0, m1, m2, var);

    float* ov = out + (size_t)n * 4 + (size_t)p * 7;
    ov[0] = sharp;
    ov[1] = a0;
    ov[2] = a1;
    ov[3] = a2;
    ov[4] = amp0;
    ov[5] = amp1;
    ov[6] = amp2;
}

// ---------- fallback (ws too small): round-2 two-table kernel ----------
__global__ __launch_bounds__(256)
void vapl_grid_kernel(const float* __restrict__ pos,
                      const float4* __restrict__ gauss,
                      const float4* __restrict__ vmf,
                      float* __restrict__ out,
                      int n)
{
    int p = blockIdx.x * blockDim.x + threadIdx.x;
    if (p >= n) return;

    float px = pos[3 * p + 0];
    float py = pos[3 * p + 1];
    float pz = pos[3 * p + 2];

    float x = ((px + 10.0f) / 20.0f) * 128.0f;
    float y = ((py + 10.0f) / 20.0f) * 128.0f;
    float z = ((pz + 10.0f) / 20.0f) * 128.0f;

    float fx = floorf(x), fy = floorf(y), fz = floorf(z);
    int ix = (int)fx, iy = (int)fy, iz = (int)fz;
    float wx = x - fx, wy = y - fy, wz = z - fz;

    float ax[4] = {1.0f - wx, 1.0f, 1.0f, wx};
    float ay[4] = {1.0f - wy, 1.0f, 1.0f, wy};
    float az[4] = {1.0f - wz, 1.0f, 1.0f, wz};

    uint32_t hx[4], hy[4], hz[4];
#pragma unroll
    for (int i = 0; i < 4; ++i) {
        hx[i] = (uint32_t)(ix - 1 + i);
        hy[i] = (uint32_t)(iy - 1 + i) * P2;
        hz[i] = (uint32_t)(iz - 1 + i) * P3;
    }

    float tg0 = 0.f, tg1 = 0.f, tg2 = 0.f, tg3 = 0.f;
    float tv0 = 0.f, tv1 = 0.f, tv2 = 0.f, tv3 = 0.f;
    float tv4 = 0.f, tv5 = 0.f, tv6 = 0.f, tv7 = 0.f;

    for (int k = 0; k < 4; ++k) {
        for (int j = 0; j < 4; ++j) {
            uint32_t hyz = hy[j] ^ hz[k];
            float wyz = ay[j] * az[k];
#pragma unroll
            for (int i = 0; i < 4; ++i) {
                uint32_t h = (hx[i] ^ hyz) & TABLE_MASK;
                float w = ax[i] * wyz;
                float4 g  = gauss[h];
                float4 v0 = vmf[(size_t)2 * h];
                float4 v1 = vmf[(size_t)2 * h + 1];
                tg0 = fmaf(w, g.x,  tg0);
                tg1 = fmaf(w, g.y,  tg1);
                tg2 = fmaf(w, g.z,  tg2);
                tg3 = fmaf(w, g.w,  tg3);
                tv0 = fmaf(w, v0.x, tv0);
                tv1 = fmaf(w, v0.y, tv1);
                tv2 = fmaf(w, v0.z, tv2);
                tv3 = fmaf(w, v0.w, tv3);
                tv4 = fmaf(w, v1.x, tv4);
                tv5 = fmaf(w, v1.y, tv5);
                tv6 = fmaf(w, v1.z, tv6);
                tv7 = fmaf(w, v1.w, tv7);
            }
        }
    }

    float m0 = sigmoidf_(tg0) * 20.0f - 10.0f;
    float m1 = sigmoidf_(tg1) * 20.0f - 10.0f;
    float m2 = sigmoidf_(tg2) * 20.0f - 10.0f;
    float var = fmaxf(tg3, 0.0f) + log1pf(expf(-fabsf(tg3)));

    float sharp = expf(tv0);
    float nrm = fmaxf(sqrtf(tv1 * tv1 + tv2 * tv2 + tv3 * tv3), 1e-12f);
    float a0 = tv1 / nrm, a1 = tv2 / nrm, a2 = tv3 / nrm;
    float amp0 = sigmoidf_(tv4);
    float amp1 = sigmoidf_(tv5);
    float amp2 = sigmoidf_(tv6);

    float* og = out + (size_t)p * 4;
    og[0] = m0;
    og[1] = m1;
    og[2] = m2;
    og[3] = var;

    float* ov = out + (size_t)n * 4 + (size_t)p * 7;
    ov[0] = sharp;
    ov[1] = a0;
    ov[2] = a1;
    ov[3] = a2;
    ov[4] = amp0;
    ov[5] = amp1;
    ov[6] = amp2;
}

extern "C" void kernel_launch(void* const* d_in, const int* in_sizes, int n_in,
                              void* d_out, int out_size, void* d_ws, size_t ws_size,
                              hipStream_t stream) {
    const float*  pos   = (const float*)d_in[0];
    const float4* gauss = (const float4*)d_in[1];
    const float4* vmf   = (const float4*)d_in[2];
    float* out = (float*)d_out;
    int n = in_sizes[0] / 3;   // 1048576

    // d_ws layout
    size_t off = 0;
    char* ws = (char*)d_ws;
    const size_t exdy_uints = (size_t)128 * 128 * ZE * 24;        // 51.9M uints = ~208 MB
    uint32_t* exdy   = (uint32_t*)(ws + off);  off += exdy_uints * 4;
    off = (off + 255) & ~(size_t)255;
    uint32_t* hist   = (uint32_t*)(ws + off);  off += (size_t)NB2 * 4;
    uint32_t* cursor = (uint32_t*)(ws + off);  off += (size_t)NB2 * 4;
    uint32_t* sums   = (uint32_t*)(ws + off);  off += 64 * 4;
    uint32_t* offs   = (uint32_t*)(ws + off);  off += 64 * 4;
    off = (off + 255) & ~(size_t)255;
    float4* sortedPts = (float4*)(ws + off);   off += (size_t)n * 16;   // 16 MB
    const size_t need = off;                                            // ~224.4 MB

    dim3 block(256);
    dim3 grid((n + 255) / 256);

    if (ws_size >= need) {
        hipLaunchKernelGGL(build_exdy_kernel, dim3(16 * ZE), block, 0, stream, gauss, vmf, exdy);
        hipMemsetAsync(hist, 0, (size_t)NB2 * 4, stream);
        hipLaunchKernelGGL(hist_kernel, grid, block, 0, stream, pos, hist, n);
        hipLaunchKernelGGL(scanA_kernel, dim3(SCAN2), dim3(1024), 0, stream, hist, cursor, sums);
        hipLaunchKernelGGL(scanB_kernel, dim3(1), dim3(SCAN2), 0, stream, sums, offs);
        hipLaunchKernelGGL(scatter_kernel, grid, block, 0, stream, pos, cursor, offs, sortedPts, n);
        hipLaunchKernelGGL(vapl_grid_sorted_kernel, grid, block, 0, stream,
                           sortedPts, exdy, out, n);
    } else {
        hipLaunchKernelGGL(vapl_grid_kernel, grid, block, 0, stream, pos, gauss, vmf, out, n);
    }
}

// Round 10
// 260.479 us; speedup vs baseline: 1.3388x; 1.3388x over previous
//
#include <hip/hip_runtime.h>
#include <hip/hip_fp16.h>
#include <cstdint>

#define TABLE_MASK 0x3FFFFFu   // 2^22 - 1
#define P2 2654435761u
#define P3 805459861u

#define XD 128                  // exdx x-extent (cx-1, cx in [1,128])
#define YD 132                  // cy in [1,131]
#define ZD 132                  // cz in [1,131]
#define RECU 12                 // 12 uints = 48 B per cell: Ex(6 half2) + Dx(6 half2)
#define NB3 (128 * 128 * 8)     // bins: (iz, iy, ix/16) raster = 131072
#define SCAN_BLKS (NB3 / 1024)  // 128
#define BUILD_BLKS (131 * 66)   // 8646

__device__ __forceinline__ float sigmoidf_(float x) { return 1.0f / (1.0f + expf(-x)); }

__device__ __forceinline__ uint32_t f2h2(float a, float b) {
    __half2 h = __floats2half2_rn(a, b);
    return *reinterpret_cast<uint32_t*>(&h);
}
__device__ __forceinline__ __half2 u2h2(uint32_t u) {
    return *reinterpret_cast<__half2*>(&u);
}

// ---------- sort key: raster (iz, iy, ix/16) ----------
__device__ __forceinline__ int bin_key3(float px, float py, float pz)
{
    float x = ((px + 10.0f) / 20.0f) * 128.0f;
    float y = ((py + 10.0f) / 20.0f) * 128.0f;
    float z = ((pz + 10.0f) / 20.0f) * 128.0f;
    int ix = min(max((int)floorf(x), 0), 127);
    int iy = min(max((int)floorf(y), 0), 127);
    int iz = min(max((int)floorf(z), 0), 127);
    return (((iz << 7) + iy) << 3) + (ix >> 4);
}

// ---------- fused prepass: build exdx volume  +  histogram (independent work) ----------
__global__ __launch_bounds__(256)
void build_hist_kernel(const float4* __restrict__ gauss,
                       const float4* __restrict__ vmf,
                       uint32_t* __restrict__ exdx,
                       const float* __restrict__ pos,
                       uint32_t* __restrict__ hist, int n)
{
    if (blockIdx.x >= BUILD_BLKS) {
        // ---- histogram part ----
        int p = (blockIdx.x - BUILD_BLKS) * blockDim.x + threadIdx.x;
        if (p < n) {
            int k = bin_key3(pos[3 * p], pos[3 * p + 1], pos[3 * p + 2]);
            atomicAdd(&hist[k], 1u);
        }
        return;
    }

    // ---- build part: x-combined fp16 volume exdx[cz][cy][cx-1] = {Ex, Dx} ----
    __shared__ float sm[2][131][13];
    int bidx = blockIdx.x;              // 131 z * 66 y-pairs
    int yp = bidx % 66;
    int rz = 1 + bidx / 66;             // [1,131]
    int ry0 = 1 + 2 * yp;               // [1,131] (row1 may overflow -> guarded)
    int t = threadIdx.x;

    for (int l = t; l < 262; l += 256) {
        int row = (l >= 131) ? 1 : 0;
        int cell = l - row * 131;
        int ry = ry0 + row;
        if (ry <= 131) {
            int xc = 1 + cell;
            uint32_t ux = (uint32_t)(xc - 2);
            uint32_t uy = (uint32_t)(ry - 2);
            uint32_t uz = (uint32_t)(rz - 2);
            uint32_t h = (ux ^ (uy * P2) ^ (uz * P3)) & TABLE_MASK;
            float4 g  = gauss[h];
            float4 v0 = vmf[(size_t)2 * h];
            float4 v1 = vmf[(size_t)2 * h + 1];
            float* s = sm[row][cell];
            s[0] = g.x;  s[1] = g.y;  s[2]  = g.z;  s[3]  = g.w;
            s[4] = v0.x; s[5] = v0.y; s[6]  = v0.z; s[7]  = v0.w;
            s[8] = v1.x; s[9] = v1.y; s[10] = v1.z; s[11] = v1.w;
        }
    }
    __syncthreads();

    int row = t >> 7;
    int c   = t & 127;
    int ry  = ry0 + row;
    if (ry > 131) return;

    uint32_t rec[12];
#pragma unroll
    for (int m = 0; m < 6; ++m) {
        float e0 = sm[row][c][2*m]   + sm[row][c+1][2*m]   + sm[row][c+2][2*m];
        float e1 = sm[row][c][2*m+1] + sm[row][c+1][2*m+1] + sm[row][c+2][2*m+1];
        float d0 = sm[row][c+3][2*m]   - sm[row][c][2*m];
        float d1 = sm[row][c+3][2*m+1] - sm[row][c][2*m+1];
        rec[m]     = f2h2(e0, e1);
        rec[6 + m] = f2h2(d0, d1);
    }
    size_t o = (((size_t)rz * YD + (size_t)ry) * XD + (size_t)c) * RECU;
    *(uint4*)(exdx + o)     = make_uint4(rec[0], rec[1], rec[2],  rec[3]);
    *(uint4*)(exdx + o + 4) = make_uint4(rec[4], rec[5], rec[6],  rec[7]);
    *(uint4*)(exdx + o + 8) = make_uint4(rec[8], rec[9], rec[10], rec[11]);
}

// ---------- scanA: per-1024-chunk exclusive prefix + chunk sums ----------
__global__ __launch_bounds__(1024)
void scanA_kernel(const uint32_t* __restrict__ hist,
                  uint32_t* __restrict__ cursor,
                  uint32_t* __restrict__ sums)
{
    __shared__ uint32_t buf[1024];
    int t = threadIdx.x;
    int base = blockIdx.x * 1024;
    uint32_t v = hist[base + t];
    buf[t] = v;
    __syncthreads();
    for (int off = 1; off < 1024; off <<= 1) {
        uint32_t x = (t >= off) ? buf[t - off] : 0u;
        __syncthreads();
        buf[t] += x;
        __syncthreads();
    }
    cursor[base + t] = buf[t] - v;
    if (t == 1023) sums[blockIdx.x] = buf[t];
}

// ---------- scatter: redundant in-block scan of 128 chunk sums, then place ----------
__global__ __launch_bounds__(256)
void scatter_kernel(const float* __restrict__ pos,
                    uint32_t* __restrict__ cursor,
                    const uint32_t* __restrict__ sums,
                    float4* __restrict__ sortedPts, int n)
{
    __shared__ uint32_t soff[SCAN_BLKS];   // inclusive scan of sums
    int t = threadIdx.x;
    if (t < SCAN_BLKS) soff[t] = sums[t];
    __syncthreads();
    for (int off = 1; off < SCAN_BLKS; off <<= 1) {
        uint32_t v = 0;
        if (t < SCAN_BLKS && t >= off) v = soff[t - off];
        __syncthreads();
        if (t < SCAN_BLKS) soff[t] += v;
        __syncthreads();
    }

    int p = blockIdx.x * blockDim.x + t;
    if (p >= n) return;
    float px = pos[3 * p], py = pos[3 * p + 1], pz = pos[3 * p + 2];
    int k = bin_key3(px, py, pz);
    int chunk = k >> 10;
    uint32_t base = (chunk > 0) ? soff[chunk - 1] : 0u;
    uint32_t slot = base + atomicAdd(&cursor[k], 1u);
    sortedPts[slot] = make_float4(px, py, pz, __uint_as_float((uint32_t)p));
}

// ---------- main: 16 cell-gathers per point, all 48 loads issued up front ----------
__device__ __forceinline__ void consume_cell(const uint4& A, const uint4& B, const uint4& C,
                                             __half2 wxh, float w, float* acc)
{
    uint32_t e[6] = {A.x, A.y, A.z, A.w, B.x, B.y};
    uint32_t d[6] = {B.z, B.w, C.x, C.y, C.z, C.w};
#pragma unroll
    for (int m = 0; m < 6; ++m) {
        __half2 v = __hfma2(wxh, u2h2(d[m]), u2h2(e[m]));
        float2 f = __half22float2(v);
        acc[2*m]     = fmaf(w, f.x, acc[2*m]);
        acc[2*m + 1] = fmaf(w, f.y, acc[2*m + 1]);
    }
}

__global__ __launch_bounds__(256, 2)
void vapl_grid_sorted_kernel(const float4* __restrict__ sortedPts,
                             const uint32_t* __restrict__ exdx,
                             float* __restrict__ out,   // [N*4] then [N*7], f32
                             int n)
{
    int bid = blockIdx.x;
    int nb  = gridDim.x;
    int b2  = ((nb & 7) == 0) ? ((bid & 7) * (nb >> 3) + (bid >> 3)) : bid;
    int s = b2 * (int)blockDim.x + (int)threadIdx.x;
    if (s >= n) return;

    float4 pt = sortedPts[s];
    int p = (int)__float_as_uint(pt.w);

    float x = ((pt.x + 10.0f) / 20.0f) * 128.0f;
    float y = ((pt.y + 10.0f) / 20.0f) * 128.0f;
    float z = ((pt.z + 10.0f) / 20.0f) * 128.0f;

    float fx = floorf(x), fy = floorf(y), fz = floorf(z);
    int ix = (int)fx, iy = (int)fy, iz = (int)fz;
    float wx = x - fx, wy = y - fy, wz = z - fz;

    float ay[4] = {1.0f - wy, 1.0f, 1.0f, wy};
    float az[4] = {1.0f - wz, 1.0f, 1.0f, wz};
    __half2 wxh = __float2half2_rn(wx);

    int bx = ix + 1, by = iy + 1, bz = iz + 1;

    uint32_t idx16[16];
    float    w16[16];
#pragma unroll
    for (int k = 0; k < 4; ++k) {
#pragma unroll
        for (int j = 0; j < 4; ++j) {
            idx16[k*4 + j] = (((uint32_t)(bz + k) * YD + (uint32_t)(by + j)) * XD
                              + (uint32_t)(bx - 1)) * RECU;
            w16[k*4 + j] = ay[j] * az[k];
        }
    }

    float acc[12] = {0.f,0.f,0.f,0.f,0.f,0.f,0.f,0.f,0.f,0.f,0.f,0.f};

    // issue ALL 48 loads before any consume (two 8-cell halves, static indexing)
    uint4 A[8][3], B[8][3];
#pragma unroll
    for (int c = 0; c < 8; ++c) {
        const uint32_t* r = exdx + idx16[c];
        A[c][0] = *(const uint4*)(r);
        A[c][1] = *(const uint4*)(r + 4);
        A[c][2] = *(const uint4*)(r + 8);
    }
#pragma unroll
    for (int c = 0; c < 8; ++c) {
        const uint32_t* r = exdx + idx16[8 + c];
        B[c][0] = *(const uint4*)(r);
        B[c][1] = *(const uint4*)(r + 4);
        B[c][2] = *(const uint4*)(r + 8);
    }
#pragma unroll
    for (int c = 0; c < 8; ++c)
        consume_cell(A[c][0], A[c][1], A[c][2], wxh, w16[c], acc);
#pragma unroll
    for (int c = 0; c < 8; ++c)
        consume_cell(B[c][0], B[c][1], B[c][2], wxh, w16[8 + c], acc);

    float m0 = sigmoidf_(acc[0]) * 20.0f - 10.0f;
    float m1 = sigmoidf_(acc[1]) * 20.0f - 10.0f;
    float m2 = sigmoidf_(acc[2]) * 20.0f - 10.0f;
    float var = fmaxf(acc[3], 0.0f) + log1pf(expf(-fabsf(acc[3])));

    float sharp = expf(acc[4]);
    float nrm = fmaxf(sqrtf(acc[5]*acc[5] + acc[6]*acc[6] + acc[7]*acc[7]), 1e-12f);
    float a0 = acc[5] / nrm, a1 = acc[6] / nrm, a2 = acc[7] / nrm;
    float amp0 = sigmoidf_(acc[8]);
    float amp1 = sigmoidf_(acc[9]);
    float amp2 = sigmoidf_(acc[10]);

    float* og = out + (size_t)p * 4;
    *(float4*)og = make_float4(m0, m1, m2, var);

    float* ov = out + (size_t)n * 4 + (size_t)p * 7;
    ov[0] = sharp;
    ov[1] = a0;
    ov[2] = a1;
    ov[3] = a2;
    ov[4] = amp0;
    ov[5] = amp1;
    ov[6] = amp2;
}

// ---------- fallback (ws too small): round-2 two-table kernel ----------
__global__ __launch_bounds__(256)
void vapl_grid_kernel(const float* __restrict__ pos,
                      const float4* __restrict__ gauss,
                      const float4* __restrict__ vmf,
                      float* __restrict__ out,
                      int n)
{
    int p = blockIdx.x * blockDim.x + threadIdx.x;
    if (p >= n) return;

    float px = pos[3 * p + 0];
    float py = pos[3 * p + 1];
    float pz = pos[3 * p + 2];

    float x = ((px + 10.0f) / 20.0f) * 128.0f;
    float y = ((py + 10.0f) / 20.0f) * 128.0f;
    float z = ((pz + 10.0f) / 20.0f) * 128.0f;

    float fx = floorf(x), fy = floorf(y), fz = floorf(z);
    int ix = (int)fx, iy = (int)fy, iz = (int)fz;
    float wx = x - fx, wy = y - fy, wz = z - fz;

    float ax[4] = {1.0f - wx, 1.0f, 1.0f, wx};
    float ay[4] = {1.0f - wy, 1.0f, 1.0f, wy};
    float az[4] = {1.0f - wz, 1.0f, 1.0f, wz};

    uint32_t hx[4], hy[4], hz[4];
#pragma unroll
    for (int i = 0; i < 4; ++i) {
        hx[i] = (uint32_t)(ix - 1 + i);
        hy[i] = (uint32_t)(iy - 1 + i) * P2;
        hz[i] = (uint32_t)(iz - 1 + i) * P3;
    }

    float tg0 = 0.f, tg1 = 0.f, tg2 = 0.f, tg3 = 0.f;
    float tv0 = 0.f, tv1 = 0.f, tv2 = 0.f, tv3 = 0.f;
    float tv4 = 0.f, tv5 = 0.f, tv6 = 0.f, tv7 = 0.f;

    for (int k = 0; k < 4; ++k) {
        for (int j = 0; j < 4; ++j) {
            uint32_t hyz = hy[j] ^ hz[k];
            float wyz = ay[j] * az[k];
#pragma unroll
            for (int i = 0; i < 4; ++i) {
                uint32_t h = (hx[i] ^ hyz) & TABLE_MASK;
                float w = ax[i] * wyz;
                float4 g  = gauss[h];
                float4 v0 = vmf[(size_t)2 * h];
                float4 v1 = vmf[(size_t)2 * h + 1];
                tg0 = fmaf(w, g.x,  tg0);
                tg1 = fmaf(w, g.y,  tg1);
                tg2 = fmaf(w, g.z,  tg2);
                tg3 = fmaf(w, g.w,  tg3);
                tv0 = fmaf(w, v0.x, tv0);
                tv1 = fmaf(w, v0.y, tv1);
                tv2 = fmaf(w, v0.z, tv2);
                tv3 = fmaf(w, v0.w, tv3);
                tv4 = fmaf(w, v1.x, tv4);
                tv5 = fmaf(w, v1.y, tv5);
                tv6 = fmaf(w, v1.z, tv6);
                tv7 = fmaf(w, v1.w, tv7);
            }
        }
    }

    float m0 = sigmoidf_(tg0) * 20.0f - 10.0f;
    float m1 = sigmoidf_(tg1) * 20.0f - 10.0f;
    float m2 = sigmoidf_(tg2) * 20.0f - 10.0f;
    float var = fmaxf(tg3, 0.0f) + log1pf(expf(-fabsf(tg3)));

    float sharp = expf(tv0);
    float nrm = fmaxf(sqrtf(tv1 * tv1 + tv2 * tv2 + tv3 * tv3), 1e-12f);
    float a0 = tv1 / nrm, a1 = tv2 / nrm, a2 = tv3 / nrm;
    float amp0 = sigmoidf_(tv4);
    float amp1 = sigmoidf_(tv5);
    float amp2 = sigmoidf_(tv6);

    float* og = out + (size_t)p * 4;
    og[0] = m0;
    og[1] = m1;
    og[2] = m2;
    og[3] = var;

    float* ov = out + (size_t)n * 4 + (size_t)p * 7;
    ov[0] = sharp;
    ov[1] = a0;
    ov[2] = a1;
    ov[3] = a2;
    ov[4] = amp0;
    ov[5] = amp1;
    ov[6] = amp2;
}

extern "C" void kernel_launch(void* const* d_in, const int* in_sizes, int n_in,
                              void* d_out, int out_size, void* d_ws, size_t ws_size,
                              hipStream_t stream) {
    const float*  pos   = (const float*)d_in[0];
    const float4* gauss = (const float4*)d_in[1];
    const float4* vmf   = (const float4*)d_in[2];
    float* out = (float*)d_out;
    int n = in_sizes[0] / 3;   // 1048576

    // d_ws layout
    size_t off = 0;
    char* ws = (char*)d_ws;
    uint32_t* exdx   = (uint32_t*)(ws + off);  off += (size_t)XD * YD * ZD * RECU * 4;  // ~107 MB
    off = (off + 255) & ~(size_t)255;
    uint32_t* hist   = (uint32_t*)(ws + off);  off += (size_t)NB3 * 4;
    uint32_t* cursor = (uint32_t*)(ws + off);  off += (size_t)NB3 * 4;
    uint32_t* sums   = (uint32_t*)(ws + off);  off += 256 * 4;
    off = (off + 255) & ~(size_t)255;
    float4* sortedPts = (float4*)(ws + off);   off += (size_t)n * 16;                   // 16 MB
    const size_t need = off;

    dim3 block(256);
    dim3 grid((n + 255) / 256);

    if (ws_size >= need) {
        hipMemsetAsync(hist, 0, (size_t)NB3 * 4, stream);
        hipLaunchKernelGGL(build_hist_kernel, dim3(BUILD_BLKS + 4096), block, 0, stream,
                           gauss, vmf, exdx, pos, hist, n);
        hipLaunchKernelGGL(scanA_kernel, dim3(SCAN_BLKS), dim3(1024), 0, stream, hist, cursor, sums);
        hipLaunchKernelGGL(scatter_kernel, grid, block, 0, stream, pos, cursor, sums, sortedPts, n);
        hipLaunchKernelGGL(vapl_grid_sorted_kernel, grid, block, 0, stream,
                           sortedPts, exdx, out, n);
    } else {
        hipLaunchKernelGGL(vapl_grid_kernel, grid, block, 0, stream, pos, gauss, vmf, out, n);
    }
}